// Round 10
// baseline (1456.566 us; speedup 1.0000x reference)
//
#include <hip/hip_runtime.h>
#include <hip/hip_bf16.h>
#include <stdint.h>

typedef __attribute__((ext_vector_type(4))) float f32x4;
typedef __attribute__((ext_vector_type(8))) unsigned short ushort8;
typedef __attribute__((ext_vector_type(2))) unsigned long long ull2;

#define BSZ 512
#define KTOT 49152
#define KSPLIT 48
#define KCHUNK 1024            /* fp8 elems per K-slice */
#define BK 128                 /* fp8 elems per K-step */
#define NKSTEP (KCHUNK / BK)   /* 8 */
#define NTILE 10
#define NPROD 512              /* producer blocks (1 row each) */
#define NCONS (NTILE * KSPLIT) /* 480 consumer (GEMM) blocks */
#define NKP 24                 /* publish granularity: 2 K-slices */
#define TSIZE (128 * 128)
#define SKEW 5
#define NPAIRS 130816.0f

__device__ __forceinline__ float bf2f(ushort u) {
    return __uint_as_float(((uint32_t)u) << 16);
}

__device__ __forceinline__ ushort f2bf(float f) {
    uint32_t u = __float_as_uint(f);
    uint32_t r = (u + 0x7fffu + ((u >> 16) & 1u)) >> 16;
    return (ushort)r;
}

__device__ __forceinline__ void gload_lds16(const uint8_t* g, uint8_t* l) {
    __builtin_amdgcn_global_load_lds(
        (const __attribute__((address_space(1))) uint32_t*)g,
        (__attribute__((address_space(3))) uint32_t*)l, 16, 0, 0);
}

// ---- Fused convert+GEMM, ALL-RESIDENT producer-consumer ----
// 992 blocks @ __launch_bounds__(256,4) -> 4 blocks/CU guaranteed
// (LDS 4x32KB=128<=160KB, VGPR<=128), 1024 slots >= 992: every block is
// co-resident REGARDLESS of dispatch order -> no starvation, no deadlock;
// worst case degenerates to serial convert-then-GEMM (= R8 performance).
// blocks [0,512): producer, block r converts row r of W (fp8, permuted),
//   publishing 24 slice-pairs via cnt[kp] (target 512 each).
// blocks [512,992): consumer (tile,ks) = R8's proven fp8 GEMM after one
//   spin-wait on cnt[ks/2].
__global__ __launch_bounds__(256, 4) void fused_kernel(
    const float* __restrict__ e, const float* __restrict__ a,
    const float* __restrict__ c, uint8_t* __restrict__ W,
    ushort* __restrict__ P, float* __restrict__ Pd, int* __restrict__ cnt) {
    __shared__ uint8_t As[128 * 128];
    __shared__ uint8_t Bs[128 * 128];
    const int b = blockIdx.x;
    const int t = threadIdx.x;

    if (b < NPROD) {
        // ================= producer: convert row b =================
        const int r = b;
#pragma unroll 1
        for (int kp = 0; kp < NKP; ++kp) {
            const int k0 = kp * 2048 + t * 8;       // logical k, 8-aligned
            const int f = k0 >> 14;                 // field uniform per step
            const int col = k0 & 16383;
            const float* src = (f == 0) ? e : (f == 1 ? a : c);
            const float* p = src + (size_t)r * 16384 + col;
            float4 v0 = reinterpret_cast<const float4*>(p)[0];
            float4 v1 = reinterpret_cast<const float4*>(p)[1];
            uint lo = __builtin_amdgcn_cvt_pk_fp8_f32(v0.x, v0.y, 0, false);
            lo = __builtin_amdgcn_cvt_pk_fp8_f32(v0.z, v0.w, lo, true);
            uint hi = __builtin_amdgcn_cvt_pk_fp8_f32(v1.x, v1.y, 0, false);
            hi = __builtin_amdgcn_cvt_pk_fp8_f32(v1.z, v1.w, hi, true);
            // permute: logical k = 64H+32s+8q+b -> phys 64H+16q+8s+b
            const int q = (k0 >> 3) & 3, s8 = (k0 >> 5) & 1;
            const size_t phys = (size_t)r * KTOT + (k0 & ~63) + q * 16 + s8 * 8;
            uint2 wv = {lo, hi};
            *reinterpret_cast<uint2*>(&W[phys]) = wv;
            __threadfence();                        // flush this thread's stores
            __syncthreads();                        // whole block done with kp
            if (t == 0) atomicAdd(&cnt[kp], 1);     // publish
        }
        return;
    }

    // ================= consumer: GEMM (tile, ks) =================
    const int ci = b - NPROD;
    const int tile = ci / KSPLIT;
    const int ks   = ci % KSPLIT;
    int ti = 0, rem = tile;
    while (rem >= 4 - ti) { rem -= 4 - ti; ++ti; }
    const int tj = ti + rem;
    const bool diag = (ti == tj);
    const int brow = ti * 128, bcol = tj * 128;
    const int kbase = ks * KCHUNK;

    if (t == 0) {
        while (atomicAdd(&cnt[ks >> 1], 0) < NPROD)
            __builtin_amdgcn_s_sleep(16);
    }
    __syncthreads();
    __threadfence();   // acquire: invalidate stale L1/L2 lines for W

    const int lane = t & 63, wid = t >> 6;
    const int wr = (wid >> 1) * 64, wc = (wid & 1) * 64;
    const bool skipw = diag && (wr == 64) && (wc == 0);

    const int grow = t >> 3, s = t & 7;
    const int swz = (s ^ (grow & 7)) * 16;          // bytes
    const uint8_t* pa = W + (size_t)(brow + grow) * KTOT + kbase + swz;
    const uint8_t* pb = W + (size_t)(bcol + grow) * KTOT + kbase + swz;
    uint8_t* la = &As[t * 16];
    uint8_t* lb = &Bs[t * 16];

    const f32x4 zero = {0.f, 0.f, 0.f, 0.f};
    f32x4 acc[4][4];
#pragma unroll
    for (int m = 0; m < 4; ++m)
#pragma unroll
        for (int n = 0; n < 4; ++n) acc[m][n] = zero;

#pragma unroll 1
    for (int kt = 0; kt < NKSTEP; ++kt) {
        const int kk = kt * BK;
#pragma unroll
        for (int i = 0; i < 4; ++i)
            gload_lds16(pa + (size_t)(i * 32) * KTOT + kk, la + i * 4096);
        if (!diag) {
#pragma unroll
            for (int i = 0; i < 4; ++i)
                gload_lds16(pb + (size_t)(i * 32) * KTOT + kk, lb + i * 4096);
        }
        __syncthreads();
        if (!skipw) {
            const uint8_t* Bsrc = diag ? As : Bs;
#pragma unroll
            for (int half = 0; half < 2; ++half) {
                ull2 af[4], bfv[4];
                const int kq = half * 4 + (lane >> 4);
#pragma unroll
                for (int m = 0; m < 4; ++m) {
                    const int row = wr + m * 16 + (lane & 15);
                    const int gg = kq ^ (row & 7);
                    af[m] = *reinterpret_cast<const ull2*>(&As[row * 128 + gg * 16]);
                }
#pragma unroll
                for (int n = 0; n < 4; ++n) {
                    const int row = wc + n * 16 + (lane & 15);
                    const int gg = kq ^ (row & 7);
                    bfv[n] = *reinterpret_cast<const ull2*>(&Bsrc[row * 128 + gg * 16]);
                }
#pragma unroll
                for (int m = 0; m < 4; ++m)
#pragma unroll
                    for (int n = 0; n < 4; ++n) {
                        acc[m][n] = __builtin_amdgcn_mfma_f32_16x16x32_fp8_fp8(
                            (long long)af[m][0], (long long)bfv[n][0], acc[m][n], 0, 0, 0);
                        acc[m][n] = __builtin_amdgcn_mfma_f32_16x16x32_fp8_fp8(
                            (long long)af[m][1], (long long)bfv[n][1], acc[m][n], 0, 0, 0);
                    }
            }
        }
        __syncthreads();
    }

    if (!skipw) {
        ushort* Pk = P + (size_t)(tile * KSPLIT + ks) * TSIZE;
        const int ci2 = (lane >> 4) * 4, cj = lane & 15;
#pragma unroll
        for (int m = 0; m < 4; ++m)
#pragma unroll
            for (int n = 0; n < 4; ++n)
#pragma unroll
                for (int r = 0; r < 4; ++r) {
                    const int li = wr + m * 16 + ci2 + r;
                    const int lj = wc + n * 16 + cj;
                    const int pr = (li + SKEW * ks) & 127;
                    Pk[pr * 128 + lj] = f2bf(acc[m][n][r]);
                    if (diag && li == lj)
                        Pd[ks * BSZ + brow + li] = acc[m][n][r];
                }
    }
}

// ---- Fused DIAG + G-reduce + pair hinge. 128 blocks x 256 thr ----
__global__ __launch_bounds__(256) void pairred_kernel(
    const ushort* __restrict__ P, const float* __restrict__ Pd,
    const int* __restrict__ tg, float* __restrict__ LP) {
    __shared__ float sd[BSZ];
    const int t = threadIdx.x;
    // phase A: DIAG (redundant per block; Pd is 98 KB, L2-hot, coalesced)
    float d0 = 0.f, d1 = 0.f;
#pragma unroll 8
    for (int k = 0; k < KSPLIT; ++k) {
        d0 += Pd[k * BSZ + t];
        d1 += Pd[k * BSZ + t + 256];
    }
    sd[t] = d0;
    sd[t + 256] = d1;
    __syncthreads();

    // phase B: on-the-fly G reduce + hinge
    const int gid = blockIdx.x * 256 + t;
    const int i = gid >> 6;
    const int j0 = (gid & 63) * 8;
    float local = 0.f;
    if (j0 + 7 > i) {
        const int ti2 = i >> 7, tj2 = j0 >> 7;
        const int tidx = (ti2 * (9 - ti2)) / 2 + (tj2 - ti2);
        const int li = i & 127, lj0 = j0 & 127;
        const ushort* base = P + (size_t)tidx * KSPLIT * TSIZE + lj0;
        float sum[8];
#pragma unroll
        for (int u = 0; u < 8; ++u) sum[u] = 0.f;
        for (int k = 0; k < KSPLIT; ++k) {
            const int pr = (li + SKEW * k) & 127;
            ushort8 v = *reinterpret_cast<const ushort8*>(base + (size_t)k * TSIZE + pr * 128);
#pragma unroll
            for (int u = 0; u < 8; ++u) sum[u] += bf2f(v[u]);
        }
        const float di = sd[i];
        const int lbl = tg[i];
#pragma unroll
        for (int u = 0; u < 8; ++u) {
            const int j = j0 + u;
            if (j > i) {
                const float d = (di + sd[j] - 2.f * sum[u]) * (1.f / 16384.f);
                local += (lbl == tg[j]) ? d : fmaxf(1.f - d, 0.f);
            }
        }
    }
#pragma unroll
    for (int off = 32; off; off >>= 1) local += __shfl_down(local, off, 64);
    __shared__ float red[4];
    const int lane = t & 63, wid = t >> 6;
    if (lane == 0) red[wid] = local;
    __syncthreads();
    if (t == 0) LP[blockIdx.x] = red[0] + red[1] + red[2] + red[3];
}

__global__ void final_kernel(const float* __restrict__ LP, float* __restrict__ out) {
    const int t = threadIdx.x;  // 128
    float v = LP[t];
#pragma unroll
    for (int off = 32; off; off >>= 1) v += __shfl_down(v, off, 64);
    __shared__ float red[2];
    if ((t & 63) == 0) red[t >> 6] = v;
    __syncthreads();
    if (t == 0) out[0] = (red[0] + red[1]) * (1.f / NPAIRS);
}

extern "C" void kernel_launch(void* const* d_in, const int* in_sizes, int n_in,
                              void* d_out, int out_size, void* d_ws, size_t ws_size,
                              hipStream_t stream) {
    const float* e  = (const float*)d_in[0];
    const float* a  = (const float*)d_in[1];
    const float* c  = (const float*)d_in[2];
    const int*   tg = (const int*)d_in[3];

    uint8_t* W   = (uint8_t*)d_ws;                                  // 25.17 MB
    ushort*  P   = (ushort*)(W + (size_t)BSZ * KTOT);               // 15.73 MB
    float*   Pd  = (float*)(P + (size_t)NTILE * KSPLIT * TSIZE);    // 98.3 KB
    float*   LP  = Pd + KSPLIT * BSZ;                               // 512 B
    int*     cnt = (int*)(LP + 128);                                // 96 B
    float*   out = (float*)d_out;

    hipMemsetAsync(cnt, 0, NKP * sizeof(int), stream);
    fused_kernel<<<dim3(NPROD + NCONS), dim3(256), 0, stream>>>(
        e, a, c, W, P, Pd, cnt);
    pairred_kernel<<<dim3(128), dim3(256), 0, stream>>>(P, Pd, tg, LP);
    final_kernel<<<dim3(1), dim3(128), 0, stream>>>(LP, out);
}

// Round 11
// 56.219 us; speedup vs baseline: 25.9090x; 25.9090x over previous
//
#include <hip/hip_runtime.h>
#include <hip/hip_bf16.h>
#include <stdint.h>

typedef __attribute__((ext_vector_type(4))) float f32x4;
typedef __attribute__((ext_vector_type(8))) unsigned short ushort8;
typedef __attribute__((ext_vector_type(2))) unsigned long long ull2;

#define BSZ 512
#define KTOT 49152
#define KSPLIT 48
#define KCHUNK 1024            /* fp8 elems per K-slice */
#define BK 128                 /* fp8 elems per K-step */
#define NKSTEP (KCHUNK / BK)   /* 8 */
#define NTILE 10
#define TSIZE (128 * 128)
#define SKEW 5
#define NPAIRS 130816.0f

__device__ __forceinline__ float bf2f(ushort u) {
    return __uint_as_float(((uint32_t)u) << 16);
}

__device__ __forceinline__ ushort f2bf(float f) {
    uint32_t u = __float_as_uint(f);
    uint32_t r = (u + 0x7fffu + ((u >> 16) & 1u)) >> 16;
    return (ushort)r;
}

__device__ __forceinline__ void gload_lds16(const uint8_t* g, uint8_t* l) {
    __builtin_amdgcn_global_load_lds(
        (const __attribute__((address_space(1))) uint32_t*)g,
        (__attribute__((address_space(3))) uint32_t*)l, 16, 0, 0);
}

// ---- Pass 1: fp32 fields -> fp8 e4m3 matrix W[512][49152], PERMUTED:
// logical k = 64H + 32s + 8q + b  ->  phys byte = 64H + 16q + 8s + b
// so a GEMM lane's 16B granule read = (MFMA k-sub0, k-sub1) operands.
__global__ __launch_bounds__(256) void convert_kernel(
    const float* __restrict__ e, const float* __restrict__ a,
    const float* __restrict__ c, uint8_t* __restrict__ W) {
    const int g = blockIdx.x * 256 + threadIdx.x;   // 12288 blocks
    const int E = g * 8;
    const int f = E >> 23;                          // field (8388608 elems)
    const int rem = E & 8388607;
    const int row = rem >> 14, col = rem & 16383;
    const float* src = (f == 0) ? e : (f == 1 ? a : c);
    float4 v0 = reinterpret_cast<const float4*>(src + rem)[0];
    float4 v1 = reinterpret_cast<const float4*>(src + rem)[1];
    uint lo = __builtin_amdgcn_cvt_pk_fp8_f32(v0.x, v0.y, 0, false);
    lo = __builtin_amdgcn_cvt_pk_fp8_f32(v0.z, v0.w, lo, true);
    uint hi = __builtin_amdgcn_cvt_pk_fp8_f32(v1.x, v1.y, 0, false);
    hi = __builtin_amdgcn_cvt_pk_fp8_f32(v1.z, v1.w, hi, true);
    const int k = f * 16384 + col;                  // 8-aligned
    const int H = k >> 6, s = (k >> 5) & 1, q = (k >> 3) & 3;
    const size_t phys = (size_t)row * KTOT + H * 64 + q * 16 + s * 8;
    uint2 w = {lo, hi};
    *reinterpret_cast<uint2*>(&W[phys]) = w;
}

// ---- Pass 2: m97-structure fp8 GEMM (R8, proven) + fp32 diag partials ----
__global__ __launch_bounds__(256, 2) void gemm_kernel(
    const uint8_t* __restrict__ W, ushort* __restrict__ P, float* __restrict__ Pd) {
    const int tile = blockIdx.x / KSPLIT;
    const int ks   = blockIdx.x % KSPLIT;
    int ti = 0, rem = tile;
    while (rem >= 4 - ti) { rem -= 4 - ti; ++ti; }
    const int tj = ti + rem;
    const bool diag = (ti == tj);
    const int brow = ti * 128, bcol = tj * 128;
    const int kbase = ks * KCHUNK;

    __shared__ uint8_t As[128 * 128];
    __shared__ uint8_t Bs[128 * 128];

    const int t = threadIdx.x;
    const int lane = t & 63, wid = t >> 6;
    const int wr = (wid >> 1) * 64, wc = (wid & 1) * 64;
    const bool skipw = diag && (wr == 64) && (wc == 0);

    const int grow = t >> 3, s = t & 7;
    const int swz = (s ^ (grow & 7)) * 16;          // bytes
    const uint8_t* pa = W + (size_t)(brow + grow) * KTOT + kbase + swz;
    const uint8_t* pb = W + (size_t)(bcol + grow) * KTOT + kbase + swz;
    uint8_t* la = &As[t * 16];
    uint8_t* lb = &Bs[t * 16];

    const f32x4 zero = {0.f, 0.f, 0.f, 0.f};
    f32x4 acc[4][4];
#pragma unroll
    for (int m = 0; m < 4; ++m)
#pragma unroll
        for (int n = 0; n < 4; ++n) acc[m][n] = zero;

#pragma unroll 1
    for (int kt = 0; kt < NKSTEP; ++kt) {
        const int kk = kt * BK;
#pragma unroll
        for (int i = 0; i < 4; ++i)
            gload_lds16(pa + (size_t)(i * 32) * KTOT + kk, la + i * 4096);
        if (!diag) {
#pragma unroll
            for (int i = 0; i < 4; ++i)
                gload_lds16(pb + (size_t)(i * 32) * KTOT + kk, lb + i * 4096);
        }
        __syncthreads();
        if (!skipw) {
            const uint8_t* Bsrc = diag ? As : Bs;
#pragma unroll
            for (int half = 0; half < 2; ++half) {
                ull2 af[4], bfv[4];
                const int kq = half * 4 + (lane >> 4);
#pragma unroll
                for (int m = 0; m < 4; ++m) {
                    const int row = wr + m * 16 + (lane & 15);
                    const int gg = kq ^ (row & 7);
                    af[m] = *reinterpret_cast<const ull2*>(&As[row * 128 + gg * 16]);
                }
#pragma unroll
                for (int n = 0; n < 4; ++n) {
                    const int row = wc + n * 16 + (lane & 15);
                    const int gg = kq ^ (row & 7);
                    bfv[n] = *reinterpret_cast<const ull2*>(&Bsrc[row * 128 + gg * 16]);
                }
#pragma unroll
                for (int m = 0; m < 4; ++m)
#pragma unroll
                    for (int n = 0; n < 4; ++n) {
                        acc[m][n] = __builtin_amdgcn_mfma_f32_16x16x32_fp8_fp8(
                            (long long)af[m][0], (long long)bfv[n][0], acc[m][n], 0, 0, 0);
                        acc[m][n] = __builtin_amdgcn_mfma_f32_16x16x32_fp8_fp8(
                            (long long)af[m][1], (long long)bfv[n][1], acc[m][n], 0, 0, 0);
                    }
            }
        }
        __syncthreads();
    }

    if (!skipw) {
        ushort* Pk = P + (size_t)(tile * KSPLIT + ks) * TSIZE;
        const int ci = (lane >> 4) * 4, cj = lane & 15;
#pragma unroll
        for (int m = 0; m < 4; ++m)
#pragma unroll
            for (int n = 0; n < 4; ++n)
#pragma unroll
                for (int r = 0; r < 4; ++r) {
                    const int li = wr + m * 16 + ci + r;
                    const int lj = wc + n * 16 + cj;
                    const int pr = (li + SKEW * ks) & 127;
                    Pk[pr * 128 + lj] = f2bf(acc[m][n][r]);
                    if (diag && li == lj)
                        Pd[ks * BSZ + brow + li] = acc[m][n][r];
                }
    }
}

// ---- Fused epilogue: DIAG + G-reduce + hinge + final (last-block ticket).
// 128 blocks x 256 thr. Validated structure from R9/R10 runs. ----
__global__ __launch_bounds__(256) void pairred_kernel(
    const ushort* __restrict__ P, const float* __restrict__ Pd,
    const int* __restrict__ tg, float* __restrict__ LP,
    int* __restrict__ ticket, float* __restrict__ out) {
    __shared__ float sd[BSZ];
    __shared__ float red[4];
    __shared__ int slast;
    const int t = threadIdx.x;
    // phase A: DIAG (redundant per block; Pd is 98 KB, L2-hot, coalesced)
    float d0 = 0.f, d1 = 0.f;
#pragma unroll 8
    for (int k = 0; k < KSPLIT; ++k) {
        d0 += Pd[k * BSZ + t];
        d1 += Pd[k * BSZ + t + 256];
    }
    sd[t] = d0;
    sd[t + 256] = d1;
    __syncthreads();

    // phase B: on-the-fly G reduce + hinge
    const int gid = blockIdx.x * 256 + t;
    const int i = gid >> 6;
    const int j0 = (gid & 63) * 8;
    float local = 0.f;
    if (j0 + 7 > i) {
        const int ti2 = i >> 7, tj2 = j0 >> 7;
        const int tidx = (ti2 * (9 - ti2)) / 2 + (tj2 - ti2);
        const int li = i & 127, lj0 = j0 & 127;
        const ushort* base = P + (size_t)tidx * KSPLIT * TSIZE + lj0;
        float sum[8];
#pragma unroll
        for (int u = 0; u < 8; ++u) sum[u] = 0.f;
        for (int k = 0; k < KSPLIT; ++k) {
            const int pr = (li + SKEW * k) & 127;
            ushort8 v = *reinterpret_cast<const ushort8*>(base + (size_t)k * TSIZE + pr * 128);
#pragma unroll
            for (int u = 0; u < 8; ++u) sum[u] += bf2f(v[u]);
        }
        const float di = sd[i];
        const int lbl = tg[i];
#pragma unroll
        for (int u = 0; u < 8; ++u) {
            const int j = j0 + u;
            if (j > i) {
                const float d = (di + sd[j] - 2.f * sum[u]) * (1.f / 16384.f);
                local += (lbl == tg[j]) ? d : fmaxf(1.f - d, 0.f);
            }
        }
    }
#pragma unroll
    for (int off = 32; off; off >>= 1) local += __shfl_down(local, off, 64);
    const int lane = t & 63, wid = t >> 6;
    if (lane == 0) red[wid] = local;
    __syncthreads();
    if (t == 0) {
        LP[blockIdx.x] = red[0] + red[1] + red[2] + red[3];
        __threadfence();                       // publish LP before ticket
        slast = (atomicAdd(ticket, 1) == 127); // last block finalizes
    }
    __syncthreads();
    if (slast && t < 128) {
        __threadfence();                       // acquire all LP
        float v = LP[t];
#pragma unroll
        for (int off = 32; off; off >>= 1) v += __shfl_down(v, off, 64);
        if (t == 0) red[0] = v;
        // t in [64,128) is a second wave:
        __syncthreads();
        if (t == 64 && lane == 0) red[1] = v;
        __syncthreads();
        if (t == 0) out[0] = (red[0] + red[1]) * (1.f / NPAIRS);
    }
}

extern "C" void kernel_launch(void* const* d_in, const int* in_sizes, int n_in,
                              void* d_out, int out_size, void* d_ws, size_t ws_size,
                              hipStream_t stream) {
    const float* e  = (const float*)d_in[0];
    const float* a  = (const float*)d_in[1];
    const float* c  = (const float*)d_in[2];
    const int*   tg = (const int*)d_in[3];

    uint8_t* W   = (uint8_t*)d_ws;                                  // 25.17 MB
    ushort*  P   = (ushort*)(W + (size_t)BSZ * KTOT);               // 15.73 MB
    float*   Pd  = (float*)(P + (size_t)NTILE * KSPLIT * TSIZE);    // 98.3 KB
    float*   LP  = Pd + KSPLIT * BSZ;                               // 512 B
    int*     ticket = (int*)(LP + 128);                             // 4 B
    float*   out = (float*)d_out;

    hipMemsetAsync(ticket, 0, sizeof(int), stream);
    convert_kernel<<<dim3(12288), dim3(256), 0, stream>>>(e, a, c, W);
    gemm_kernel<<<dim3(NTILE * KSPLIT), dim3(256), 0, stream>>>(W, P, Pd);
    pairred_kernel<<<dim3(128), dim3(256), 0, stream>>>(P, Pd, tg, LP, ticket, out);
}

// Round 12
// 50.730 us; speedup vs baseline: 28.7119x; 1.1082x over previous
//
#include <hip/hip_runtime.h>
#include <hip/hip_bf16.h>
#include <stdint.h>

typedef __attribute__((ext_vector_type(4))) float f32x4;
typedef __attribute__((ext_vector_type(8))) unsigned short ushort8;
typedef __attribute__((ext_vector_type(2))) unsigned long long ull2;

#define BSZ 512
#define KTOT 49152
#define KSPLIT 48
#define KCHUNK 1024            /* fp8 elems per K-slice */
#define BK 128                 /* fp8 elems per K-step */
#define NKSTEP (KCHUNK / BK)   /* 8 */
#define NTILE 10
#define TSIZE (128 * 128)
#define SKEW 5
#define NPAIRS 130816.0f

__device__ __forceinline__ float bf2f(ushort u) {
    return __uint_as_float(((uint32_t)u) << 16);
}

__device__ __forceinline__ ushort f2bf(float f) {
    uint32_t u = __float_as_uint(f);
    uint32_t r = (u + 0x7fffu + ((u >> 16) & 1u)) >> 16;
    return (ushort)r;
}

__device__ __forceinline__ void gload_lds16(const uint8_t* g, uint8_t* l) {
    __builtin_amdgcn_global_load_lds(
        (const __attribute__((address_space(1))) uint32_t*)g,
        (__attribute__((address_space(3))) uint32_t*)l, 16, 0, 0);
}

// ---- Pass 1: fp32 fields -> fp8 e4m3 matrix W[512][49152], PERMUTED:
// logical k = 64H + 32s + 8q + b  ->  phys byte = 64H + 16q + 8s + b
// so a GEMM lane's 16B granule read = (MFMA k-sub0, k-sub1) operands.
// Also zeroes the epilogue ticket (replaces the costly 4-byte memset:
// R11 showed fillBufferAligned dispatches of ~40 us for it).
__global__ __launch_bounds__(256) void convert_kernel(
    const float* __restrict__ e, const float* __restrict__ a,
    const float* __restrict__ c, uint8_t* __restrict__ W,
    int* __restrict__ ticket) {
    if (blockIdx.x == 0 && threadIdx.x == 0) *ticket = 0;
    const int g = blockIdx.x * 256 + threadIdx.x;   // 12288 blocks
    const int E = g * 8;
    const int f = E >> 23;                          // field (8388608 elems)
    const int rem = E & 8388607;
    const int row = rem >> 14, col = rem & 16383;
    const float* src = (f == 0) ? e : (f == 1 ? a : c);
    float4 v0 = reinterpret_cast<const float4*>(src + rem)[0];
    float4 v1 = reinterpret_cast<const float4*>(src + rem)[1];
    uint lo = __builtin_amdgcn_cvt_pk_fp8_f32(v0.x, v0.y, 0, false);
    lo = __builtin_amdgcn_cvt_pk_fp8_f32(v0.z, v0.w, lo, true);
    uint hi = __builtin_amdgcn_cvt_pk_fp8_f32(v1.x, v1.y, 0, false);
    hi = __builtin_amdgcn_cvt_pk_fp8_f32(v1.z, v1.w, hi, true);
    const int k = f * 16384 + col;                  // 8-aligned
    const int H = k >> 6, s = (k >> 5) & 1, q = (k >> 3) & 3;
    const size_t phys = (size_t)row * KTOT + H * 64 + q * 16 + s * 8;
    uint2 w = {lo, hi};
    *reinterpret_cast<uint2*>(&W[phys]) = w;
}

// ---- Pass 2: m97-structure fp8 GEMM (proven) + fp32 diag partials ----
__global__ __launch_bounds__(256, 2) void gemm_kernel(
    const uint8_t* __restrict__ W, ushort* __restrict__ P, float* __restrict__ Pd) {
    const int tile = blockIdx.x / KSPLIT;
    const int ks   = blockIdx.x % KSPLIT;
    int ti = 0, rem = tile;
    while (rem >= 4 - ti) { rem -= 4 - ti; ++ti; }
    const int tj = ti + rem;
    const bool diag = (ti == tj);
    const int brow = ti * 128, bcol = tj * 128;
    const int kbase = ks * KCHUNK;

    __shared__ uint8_t As[128 * 128];
    __shared__ uint8_t Bs[128 * 128];

    const int t = threadIdx.x;
    const int lane = t & 63, wid = t >> 6;
    const int wr = (wid >> 1) * 64, wc = (wid & 1) * 64;
    const bool skipw = diag && (wr == 64) && (wc == 0);

    const int grow = t >> 3, s = t & 7;
    const int swz = (s ^ (grow & 7)) * 16;          // bytes
    const uint8_t* pa = W + (size_t)(brow + grow) * KTOT + kbase + swz;
    const uint8_t* pb = W + (size_t)(bcol + grow) * KTOT + kbase + swz;
    uint8_t* la = &As[t * 16];
    uint8_t* lb = &Bs[t * 16];

    const f32x4 zero = {0.f, 0.f, 0.f, 0.f};
    f32x4 acc[4][4];
#pragma unroll
    for (int m = 0; m < 4; ++m)
#pragma unroll
        for (int n = 0; n < 4; ++n) acc[m][n] = zero;

#pragma unroll 1
    for (int kt = 0; kt < NKSTEP; ++kt) {
        const int kk = kt * BK;
#pragma unroll
        for (int i = 0; i < 4; ++i)
            gload_lds16(pa + (size_t)(i * 32) * KTOT + kk, la + i * 4096);
        if (!diag) {
#pragma unroll
            for (int i = 0; i < 4; ++i)
                gload_lds16(pb + (size_t)(i * 32) * KTOT + kk, lb + i * 4096);
        }
        __syncthreads();
        if (!skipw) {
            const uint8_t* Bsrc = diag ? As : Bs;
#pragma unroll
            for (int half = 0; half < 2; ++half) {
                ull2 af[4], bfv[4];
                const int kq = half * 4 + (lane >> 4);
#pragma unroll
                for (int m = 0; m < 4; ++m) {
                    const int row = wr + m * 16 + (lane & 15);
                    const int gg = kq ^ (row & 7);
                    af[m] = *reinterpret_cast<const ull2*>(&As[row * 128 + gg * 16]);
                }
#pragma unroll
                for (int n = 0; n < 4; ++n) {
                    const int row = wc + n * 16 + (lane & 15);
                    const int gg = kq ^ (row & 7);
                    bfv[n] = *reinterpret_cast<const ull2*>(&Bsrc[row * 128 + gg * 16]);
                }
#pragma unroll
                for (int m = 0; m < 4; ++m)
#pragma unroll
                    for (int n = 0; n < 4; ++n) {
                        acc[m][n] = __builtin_amdgcn_mfma_f32_16x16x32_fp8_fp8(
                            (long long)af[m][0], (long long)bfv[n][0], acc[m][n], 0, 0, 0);
                        acc[m][n] = __builtin_amdgcn_mfma_f32_16x16x32_fp8_fp8(
                            (long long)af[m][1], (long long)bfv[n][1], acc[m][n], 0, 0, 0);
                    }
            }
        }
        __syncthreads();
    }

    if (!skipw) {
        ushort* Pk = P + (size_t)(tile * KSPLIT + ks) * TSIZE;
        const int ci = (lane >> 4) * 4, cj = lane & 15;
#pragma unroll
        for (int m = 0; m < 4; ++m)
#pragma unroll
            for (int n = 0; n < 4; ++n)
#pragma unroll
                for (int r = 0; r < 4; ++r) {
                    const int li = wr + m * 16 + ci + r;
                    const int lj = wc + n * 16 + cj;
                    const int pr = (li + SKEW * ks) & 127;
                    Pk[pr * 128 + lj] = f2bf(acc[m][n][r]);
                    if (diag && li == lj)
                        Pd[ks * BSZ + brow + li] = acc[m][n][r];
                }
    }
}

// ---- Fused epilogue: DIAG + G-reduce + hinge + final (last-block ticket).
// 128 blocks x 256 thr. Deterministic: fixed-order sum over LP. ----
__global__ __launch_bounds__(256) void pairred_kernel(
    const ushort* __restrict__ P, const float* __restrict__ Pd,
    const int* __restrict__ tg, float* __restrict__ LP,
    int* __restrict__ ticket, float* __restrict__ out) {
    __shared__ float sd[BSZ];
    __shared__ float red[4];
    __shared__ int slast;
    const int t = threadIdx.x;
    // phase A: DIAG (redundant per block; Pd is 98 KB, L2-hot, coalesced)
    float d0 = 0.f, d1 = 0.f;
#pragma unroll 8
    for (int k = 0; k < KSPLIT; ++k) {
        d0 += Pd[k * BSZ + t];
        d1 += Pd[k * BSZ + t + 256];
    }
    sd[t] = d0;
    sd[t + 256] = d1;
    __syncthreads();

    // phase B: on-the-fly G reduce + hinge
    const int gid = blockIdx.x * 256 + t;
    const int i = gid >> 6;
    const int j0 = (gid & 63) * 8;
    float local = 0.f;
    if (j0 + 7 > i) {
        const int ti2 = i >> 7, tj2 = j0 >> 7;
        const int tidx = (ti2 * (9 - ti2)) / 2 + (tj2 - ti2);
        const int li = i & 127, lj0 = j0 & 127;
        const ushort* base = P + (size_t)tidx * KSPLIT * TSIZE + lj0;
        float sum[8];
#pragma unroll
        for (int u = 0; u < 8; ++u) sum[u] = 0.f;
        for (int k = 0; k < KSPLIT; ++k) {
            const int pr = (li + SKEW * k) & 127;
            ushort8 v = *reinterpret_cast<const ushort8*>(base + (size_t)k * TSIZE + pr * 128);
#pragma unroll
            for (int u = 0; u < 8; ++u) sum[u] += bf2f(v[u]);
        }
        const float di = sd[i];
        const int lbl = tg[i];
#pragma unroll
        for (int u = 0; u < 8; ++u) {
            const int j = j0 + u;
            if (j > i) {
                const float d = (di + sd[j] - 2.f * sum[u]) * (1.f / 16384.f);
                local += (lbl == tg[j]) ? d : fmaxf(1.f - d, 0.f);
            }
        }
    }
#pragma unroll
    for (int off = 32; off; off >>= 1) local += __shfl_down(local, off, 64);
    const int lane = t & 63, wid = t >> 6;
    if (lane == 0) red[wid] = local;
    __syncthreads();
    if (t == 0) {
        LP[blockIdx.x] = red[0] + red[1] + red[2] + red[3];
        __threadfence();                       // publish LP before ticket
        slast = (atomicAdd(ticket, 1) == 127); // last block finalizes
    }
    __syncthreads();
    if (slast && t < 128) {
        __threadfence();                       // acquire all LP
        float v = LP[t];
#pragma unroll
        for (int off = 32; off; off >>= 1) v += __shfl_down(v, off, 64);
        if (t == 0) red[0] = v;
        __syncthreads();
        if (t == 64 && lane == 0) red[1] = v;
        __syncthreads();
        if (t == 0) out[0] = (red[0] + red[1]) * (1.f / NPAIRS);
    }
}

extern "C" void kernel_launch(void* const* d_in, const int* in_sizes, int n_in,
                              void* d_out, int out_size, void* d_ws, size_t ws_size,
                              hipStream_t stream) {
    const float* e  = (const float*)d_in[0];
    const float* a  = (const float*)d_in[1];
    const float* c  = (const float*)d_in[2];
    const int*   tg = (const int*)d_in[3];

    uint8_t* W   = (uint8_t*)d_ws;                                  // 25.17 MB
    ushort*  P   = (ushort*)(W + (size_t)BSZ * KTOT);               // 15.73 MB
    float*   Pd  = (float*)(P + (size_t)NTILE * KSPLIT * TSIZE);    // 98.3 KB
    float*   LP  = Pd + KSPLIT * BSZ;                               // 512 B
    int*     ticket = (int*)(LP + 128);                             // 4 B
    float*   out = (float*)d_out;

    convert_kernel<<<dim3(12288), dim3(256), 0, stream>>>(e, a, c, W, ticket);
    gemm_kernel<<<dim3(NTILE * KSPLIT), dim3(256), 0, stream>>>(W, P, Pd);
    pairred_kernel<<<dim3(128), dim3(256), 0, stream>>>(P, Pd, tg, LP, ticket, out);
}